// Round 6
// baseline (108.969 us; speedup 1.0000x reference)
//
#include <hip/hip_runtime.h>
#include <math.h>

#define NTR 2048
#define MTE 4096
#define DIM 16
#define TT 4
#define NT 8192          // NTR * TT
#define KIT 26           // max preconditioned PIPECG iterations
#define NBLK 256         // persistent blocks (1 per CU)
#define ROWS 8           // train rows per block
#define TOL2 1e-8f       // exit: gamma <= TOL2 * gamma0
#define TAGB 0x40000000u // tag for B publication (>> any CG tag)

typedef unsigned long long u64;

// workspace layout (float offsets; u64 regions 8B-aligned by construction)
#define OFF_A     0                       // scaled train coords  NTR x DIM
#define OFF_ANORM (OFF_A + NTR*DIM)       // row norms            NTR
#define OFF_R     (OFF_ANORM + NTR)       // initial residual     NT
#define OFF_MT    (OFF_R + NT)            // tagged m vector      u64[2*NT]
#define OFF_GT    (OFF_MT + 4*NT)         // tagged gamma parts   u64[2*NBLK]
#define OFF_DT    (OFF_GT + 4*NBLK)       // tagged delta parts   u64[2*NBLK]
#define OFF_BT    (OFF_DT + 4*NBLK)       // tagged B             u64[NT]
#define NZERO     (2*NT + 4*NBLK + NT)    // contiguous u64s to zero (25600)

__device__ __forceinline__ u64 tagw(unsigned g, float v) {
    return ((u64)g << 32) | (u64)__float_as_uint(v);
}
__device__ __forceinline__ float payf(u64 w) { return __uint_as_float((unsigned)w); }
__device__ __forceinline__ unsigned tago(u64 w) { return (unsigned)(w >> 32); }

// prep: scaled coords, norms, residual, zero all tag words.
// Kernel boundary provides grid-wide visibility for these plain stores.
__global__ void k_prep(const float* __restrict__ tx, const float* __restrict__ ty,
                       const float* __restrict__ ls, const float* __restrict__ mc,
                       float* __restrict__ a, float* __restrict__ anorm,
                       float* __restrict__ r, u64* __restrict__ tags) {
    int n = blockIdx.x * 256 + threadIdx.x;   // 8 blocks x 256 = 2048 threads
    for (int i = n; i < NZERO; i += 2048) tags[i] = 0ULL;
    float an = 0.f;
    #pragma unroll
    for (int d = 0; d < DIM; ++d) {
        float v = tx[n*DIM + d] / ls[d];
        a[n*DIM + d] = v;
        an = fmaf(v, v, an);
    }
    anorm[n] = an;
    float4 yv;
    yv.x = ty[n*4+0] - mc[0];
    yv.y = ty[n*4+1] - mc[1];
    yv.z = ty[n*4+2] - mc[2];
    yv.w = ty[n*4+3] - mc[3];
    reinterpret_cast<float4*>(r)[n] = yv;
}

// Persistent barrier-free pipelined PCG: every cross-block word is a
// {tag|fp32} u64 atomic; readers retry until tag >= expected. Slot = tag&1;
// double-buffering is safe because a writer of tag T+2 can only proceed
// after its own tag-(T+1) read succeeded, which implies all blocks consumed
// tag T. Early exit is deterministic (identical fixed-order reductions in
// every block). No fences, no flags, no grid.sync.
__global__ __launch_bounds__(256, 1) void k_pcg(
    const float* __restrict__ xte, const float* __restrict__ ls,
    const float* __restrict__ mc,
    const float* __restrict__ tf, const float* __restrict__ tv,
    const float* __restrict__ tn, const float* __restrict__ nz,
    const float* __restrict__ ag, const float* __restrict__ anormg,
    const float* __restrict__ r0g,
    u64* __restrict__ mt, u64* __restrict__ gt, u64* __restrict__ dt,
    u64* __restrict__ bt, float* __restrict__ out)
{
    __shared__ float KxxS[ROWS][NTR];      // 64 KB
    __shared__ float4 qS[NTR];             // 32 KB : Kt*m staging; later B tile
    __shared__ float arowS[ROWS][DIM];
    __shared__ float anormS[ROWS];
    __shared__ float uSm[32];
    __shared__ float xSl[32], rSl[32], uSl[32], wSl[32];
    __shared__ float pSl[32], sSl[32], zSl[32], qSl[32], mSl[32];
    __shared__ float scal[2];
    __shared__ float xrS[16][DIM];
    __shared__ float xnS[16];

    const int tid = threadIdx.x;
    const int b = blockIdx.x;
    const int wv = tid >> 6, lane = tid & 63;
    const int i0 = b * ROWS;
    const int sl = lane & 31;
    const int pbase = lane & ~3;

    const float f0=tf[0], f1=tf[1], f2=tf[2], f3=tf[3];
    const float K00=fmaf(f0,f0,tv[0]), K01=f0*f1, K02=f0*f2, K03=f0*f3;
    const float K11=fmaf(f1,f1,tv[1]), K12=f1*f2, K13=f1*f3;
    const float K22=fmaf(f2,f2,tv[2]), K23=f2*f3;
    const float K33=fmaf(f3,f3,tv[3]);
    const float dz = nz[0];
    const int   t  = lane & 3;
    const float dn_t = tn[t] + dz;
    // C = (Kt + D)^-1 row t via Sherman-Morrison
    const float g0v=tv[0]+tn[0]+dz, g1v=tv[1]+tn[1]+dz, g2v=tv[2]+tn[2]+dz, g3v=tv[3]+tn[3]+dz;
    const float c0=1.f/g0v, c1=1.f/g1v, c2=1.f/g2v, c3=1.f/g3v;
    const float up0=c0*f0, up1=c1*f1, up2=c2*f2, up3=c3*f3;
    const float rden = 1.f/(1.f + f0*up0 + f1*up1 + f2*up2 + f3*up3);
    const float upt = (t==0)?up0:(t==1)?up1:(t==2)?up2:up3;
    const float Ct0 = ((t==0)?c0:0.f) - upt*up0*rden;
    const float Ct1 = ((t==1)?c1:0.f) - upt*up1*rden;
    const float Ct2 = ((t==2)?c2:0.f) - upt*up2*rden;
    const float Ct3 = ((t==3)?c3:0.f) - upt*up3*rden;
    // Kt row t (for B = A @ Kt in the tail)
    const float Kt0 = (t==0)?K00:(t==1)?K01:(t==2)?K02:K03;
    const float Kt1 = (t==0)?K01:(t==1)?K11:(t==2)?K12:K13;
    const float Kt2 = (t==0)?K02:(t==1)?K12:(t==2)?K22:K23;
    const float Kt3 = (t==0)?K03:(t==1)?K13:(t==2)?K23:K33;

    if (tid < ROWS*DIM) arowS[tid >> 4][tid & 15] = ag[i0*DIM + tid];
    if (tid < ROWS) anormS[tid] = anormg[i0 + tid];
    __syncthreads();

    // ---- phase A: u = C r0; publish as m tag 1 + gamma_0 partial tag 1 ----
    if (wv == 0) {
        float rv = (lane < 32) ? r0g[i0*TT + lane] : 0.f;
        float r0s = __shfl(rv, pbase+0), r1s = __shfl(rv, pbase+1);
        float r2s = __shfl(rv, pbase+2), r3s = __shfl(rv, pbase+3);
        float uv = Ct0*r0s + Ct1*r1s + Ct2*r2s + Ct3*r3s;
        if (lane < 32) {
            rSl[lane]=rv; uSl[lane]=uv;
            xSl[lane]=0.f; pSl[lane]=0.f; sSl[lane]=0.f; zSl[lane]=0.f; qSl[lane]=0.f;
            __hip_atomic_store(&mt[1*NT + i0*TT + lane], tagw(1u, uv),
                               __ATOMIC_RELAXED, __HIP_MEMORY_SCOPE_AGENT);
        }
        float g = (lane < 32) ? rv*uv : 0.f;
        #pragma unroll
        for (int off = 32; off; off >>= 1) g += __shfl_down(g, off);
        if (lane == 0)
            __hip_atomic_store(&gt[1*NBLK + b], tagw(1u, g),
                               __ATOMIC_RELAXED, __HIP_MEMORY_SCOPE_AGENT);
    }

    // ---- build own Kxx rows in LDS (overlaps other blocks' publishes) ----
    for (int j = tid; j < NTR; j += 256) {
        const float4* aj4 = reinterpret_cast<const float4*>(ag + j*DIM);
        float4 A0=aj4[0], A1=aj4[1], A2=aj4[2], A3=aj4[3];
        float an = anormg[j];
        #pragma unroll
        for (int rr = 0; rr < ROWS; ++rr) {
            float dot;
            dot = arowS[rr][0]*A0.x;            dot = fmaf(arowS[rr][1], A0.y, dot);
            dot = fmaf(arowS[rr][2], A0.z, dot); dot = fmaf(arowS[rr][3], A0.w, dot);
            dot = fmaf(arowS[rr][4], A1.x, dot); dot = fmaf(arowS[rr][5], A1.y, dot);
            dot = fmaf(arowS[rr][6], A1.z, dot); dot = fmaf(arowS[rr][7], A1.w, dot);
            dot = fmaf(arowS[rr][8], A2.x, dot); dot = fmaf(arowS[rr][9], A2.y, dot);
            dot = fmaf(arowS[rr][10],A2.z, dot); dot = fmaf(arowS[rr][11],A2.w, dot);
            dot = fmaf(arowS[rr][12],A3.x, dot); dot = fmaf(arowS[rr][13],A3.y, dot);
            dot = fmaf(arowS[rr][14],A3.z, dot); dot = fmaf(arowS[rr][15],A3.w, dot);
            float d2 = anormS[rr] + an - 2.f*dot;
            KxxS[rr][j] = __expf(-0.5f * fmaxf(d2, 0.f));
        }
    }
    __syncthreads();

    // retry-read m with tag, compute q = Kt*m into qS
    auto mread = [&](unsigned tag) {
        u64* src = mt + (tag & 1u)*NT;
        for (int j = tid; j < NTR; j += 256) {
            u64* p4 = src + j*4;
            u64 w0, w1, w2, w3;
            for (;;) {
                w0 = __hip_atomic_load(p4+0, __ATOMIC_RELAXED, __HIP_MEMORY_SCOPE_AGENT);
                w1 = __hip_atomic_load(p4+1, __ATOMIC_RELAXED, __HIP_MEMORY_SCOPE_AGENT);
                w2 = __hip_atomic_load(p4+2, __ATOMIC_RELAXED, __HIP_MEMORY_SCOPE_AGENT);
                w3 = __hip_atomic_load(p4+3, __ATOMIC_RELAXED, __HIP_MEMORY_SCOPE_AGENT);
                if (tago(w0) >= tag && tago(w1) >= tag &&
                    tago(w2) >= tag && tago(w3) >= tag) break;
                __builtin_amdgcn_s_sleep(1);
            }
            float m0 = payf(w0), m1 = payf(w1), m2 = payf(w2), m3 = payf(w3);
            float4 q;
            q.x = K00*m0 + K01*m1 + K02*m2 + K03*m3;
            q.y = K01*m0 + K11*m1 + K12*m2 + K13*m3;
            q.z = K02*m0 + K12*m1 + K22*m2 + K23*m3;
            q.w = K03*m0 + K13*m1 + K23*m2 + K33*m3;
            qS[j] = q;
        }
        __syncthreads();
    };

    // own-rows kron matvec from qS -> uSm
    auto kloop = [&]() {
        float a00=0,a01=0,a02=0,a03=0,a10=0,a11=0,a12=0,a13=0;
        const int r0_ = 2*wv, r1_ = r0_ + 1;
        for (int jb = 0; jb < NTR/64; ++jb) {
            int j = jb*64 + lane;
            float4 q = qS[j];
            float k0 = KxxS[r0_][j], k1 = KxxS[r1_][j];
            a00 = fmaf(k0,q.x,a00); a01 = fmaf(k0,q.y,a01);
            a02 = fmaf(k0,q.z,a02); a03 = fmaf(k0,q.w,a03);
            a10 = fmaf(k1,q.x,a10); a11 = fmaf(k1,q.y,a11);
            a12 = fmaf(k1,q.z,a12); a13 = fmaf(k1,q.w,a13);
        }
        #pragma unroll
        for (int off = 32; off; off >>= 1) {
            a00 += __shfl_down(a00,off); a01 += __shfl_down(a01,off);
            a02 += __shfl_down(a02,off); a03 += __shfl_down(a03,off);
            a10 += __shfl_down(a10,off); a11 += __shfl_down(a11,off);
            a12 += __shfl_down(a12,off); a13 += __shfl_down(a13,off);
        }
        if (lane == 0) {
            uSm[r0_*4+0]=a00; uSm[r0_*4+1]=a01; uSm[r0_*4+2]=a02; uSm[r0_*4+3]=a03;
            uSm[r1_*4+0]=a10; uSm[r1_*4+1]=a11; uSm[r1_*4+2]=a12; uSm[r1_*4+3]=a13;
        }
        __syncthreads();
    };

    // wave0-only: retry-read 256 gamma/delta partials of `tag`, fixed-order sum
    auto scalred = [&](unsigned tag) {
        u64* gs = gt + (tag & 1u)*NBLK;
        u64* ds = dt + (tag & 1u)*NBLK;
        u64 ga[4], da[4];
        for (;;) {
            bool ok = true;
            #pragma unroll
            for (int k2 = 0; k2 < 4; ++k2) {
                ga[k2] = __hip_atomic_load(&gs[lane + 64*k2], __ATOMIC_RELAXED, __HIP_MEMORY_SCOPE_AGENT);
                da[k2] = __hip_atomic_load(&ds[lane + 64*k2], __ATOMIC_RELAXED, __HIP_MEMORY_SCOPE_AGENT);
                ok = ok && (tago(ga[k2]) >= tag) && (tago(da[k2]) >= tag);
            }
            if (__all(ok)) break;
            __builtin_amdgcn_s_sleep(1);
        }
        float g  = payf(ga[0]) + payf(ga[1]) + payf(ga[2]) + payf(ga[3]);
        float dl = payf(da[0]) + payf(da[1]) + payf(da[2]) + payf(da[3]);
        #pragma unroll
        for (int off = 32; off; off >>= 1) { g += __shfl_down(g,off); dl += __shfl_down(dl,off); }
        if (lane == 0) { scal[0] = g; scal[1] = dl; }
    };

    // ---- phase B: w = A u; m0 = C w -> m tag 2; delta_0 partial tag 1 ----
    mread(1u);
    kloop();
    if (wv == 0) {
        float uv = uSl[sl];
        float wn = uSm[sl] + dn_t * uv;
        float w0s = __shfl(wn, pbase+0), w1s = __shfl(wn, pbase+1);
        float w2s = __shfl(wn, pbase+2), w3s = __shfl(wn, pbase+3);
        float mn = Ct0*w0s + Ct1*w1s + Ct2*w2s + Ct3*w3s;
        if (lane < 32) {
            wSl[lane]=wn; mSl[lane]=mn;
            __hip_atomic_store(&mt[0*NT + i0*TT + lane], tagw(2u, mn),
                               __ATOMIC_RELAXED, __HIP_MEMORY_SCOPE_AGENT);
        }
        float dl = (lane < 32) ? wn*uv : 0.f;
        #pragma unroll
        for (int off = 32; off; off >>= 1) dl += __shfl_down(dl, off);
        if (lane == 0)
            __hip_atomic_store(&dt[1*NBLK + b], tagw(1u, dl),
                               __ATOMIC_RELAXED, __HIP_MEMORY_SCOPE_AGENT);
        scalred(1u);                      // gamma_0, delta_0 -> scal[]
    }
    __syncthreads();

    // ---- main loop: round it consumes m tag it+2 & scal from prev round,
    //      publishes m tag it+3 & partials tag it+2 ----
    float gamma_prev = 1.f, alpha_prev = 1.f, gamma0 = 0.f;
    float g1h = 1e30f, g2h = 1e30f;
    for (int it = 0; it < KIT; ++it) {
        float gam = scal[0], del = scal[1];
        if (it == 0) gamma0 = gam;
        if (!(gam > TOL2 * gamma0)) break;                 // converged / NaN
        if (it >= 6 && gam > 0.25f * g2h) break;           // fp32 stagnation
        float beta, alph;
        if (it == 0) { beta = 0.f; alph = gam / del; }
        else {
            beta = gam / gamma_prev;
            float den = del - beta * gam / alpha_prev;
            if (!(fabsf(den) > 1e-37f)) break;
            alph = gam / den;
        }

        mread((unsigned)(it + 2));
        kloop();

        if (wv == 0) {
            float mv = mSl[sl];
            float nv = uSm[sl] + dn_t * mv;            // full A m
            float zv = fmaf(beta, zSl[sl], nv);
            float qv = fmaf(beta, qSl[sl], mv);
            float sv = fmaf(beta, sSl[sl], wSl[sl]);
            float pv = fmaf(beta, pSl[sl], uSl[sl]);
            float xv = fmaf( alph, pv, xSl[sl]);
            float rv = fmaf(-alph, sv, rSl[sl]);
            float uv = fmaf(-alph, qv, uSl[sl]);
            float wn = fmaf(-alph, zv, wSl[sl]);
            float w0s = __shfl(wn, pbase+0), w1s = __shfl(wn, pbase+1);
            float w2s = __shfl(wn, pbase+2), w3s = __shfl(wn, pbase+3);
            float mn = Ct0*w0s + Ct1*w1s + Ct2*w2s + Ct3*w3s;
            if (lane < 32) {
                zSl[lane]=zv; qSl[lane]=qv; sSl[lane]=sv; pSl[lane]=pv;
                xSl[lane]=xv; rSl[lane]=rv; uSl[lane]=uv; wSl[lane]=wn; mSl[lane]=mn;
                __hip_atomic_store(&mt[((unsigned)(it+3) & 1u)*NT + i0*TT + lane],
                                   tagw((unsigned)(it+3), mn),
                                   __ATOMIC_RELAXED, __HIP_MEMORY_SCOPE_AGENT);
            }
            float g  = (lane < 32) ? rv*uv : 0.f;
            float dl = (lane < 32) ? wn*uv : 0.f;
            #pragma unroll
            for (int off = 32; off; off >>= 1) { g += __shfl_down(g,off); dl += __shfl_down(dl,off); }
            if (lane == 0) {
                __hip_atomic_store(&gt[((unsigned)(it+2) & 1u)*NBLK + b],
                                   tagw((unsigned)(it+2), g),
                                   __ATOMIC_RELAXED, __HIP_MEMORY_SCOPE_AGENT);
                __hip_atomic_store(&dt[((unsigned)(it+2) & 1u)*NBLK + b],
                                   tagw((unsigned)(it+2), dl),
                                   __ATOMIC_RELAXED, __HIP_MEMORY_SCOPE_AGENT);
            }
            scalred((unsigned)(it + 2));   // gamma/delta for round it+1
        }
        gamma_prev = gam; alpha_prev = alph;
        g2h = g1h; g1h = gam;
        __syncthreads();
    }

    // ---- tail 1: publish B slice = (x reshaped N x T) @ Kt, tag TAGB ----
    __syncthreads();
    if (tid < 32) {
        int p = tid >> 2;
        float bv = Kt0*xSl[p*4+0] + Kt1*xSl[p*4+1] + Kt2*xSl[p*4+2] + Kt3*xSl[p*4+3];
        __hip_atomic_store(&bt[i0*TT + tid], tagw(TAGB, bv),
                           __ATOMIC_RELAXED, __HIP_MEMORY_SCOPE_AGENT);
    }
    // retry-read full B into qS
    for (int j = tid; j < NTR; j += 256) {
        u64* p4 = bt + j*4;
        u64 w0, w1, w2, w3;
        for (;;) {
            w0 = __hip_atomic_load(p4+0, __ATOMIC_RELAXED, __HIP_MEMORY_SCOPE_AGENT);
            w1 = __hip_atomic_load(p4+1, __ATOMIC_RELAXED, __HIP_MEMORY_SCOPE_AGENT);
            w2 = __hip_atomic_load(p4+2, __ATOMIC_RELAXED, __HIP_MEMORY_SCOPE_AGENT);
            w3 = __hip_atomic_load(p4+3, __ATOMIC_RELAXED, __HIP_MEMORY_SCOPE_AGENT);
            if (tago(w0) >= TAGB && tago(w1) >= TAGB &&
                tago(w2) >= TAGB && tago(w3) >= TAGB) break;
            __builtin_amdgcn_s_sleep(1);
        }
        float4 Bv; Bv.x = payf(w0); Bv.y = payf(w1); Bv.z = payf(w2); Bv.w = payf(w3);
        qS[j] = Bv;
    }
    {
        int row = tid >> 4, d = tid & 15;
        xrS[row][d] = xte[(b*16 + row)*DIM + d] / ls[d];
    }
    __syncthreads();
    if (tid < 16) {
        float s = 0.f;
        #pragma unroll
        for (int d = 0; d < DIM; ++d) s = fmaf(xrS[tid][d], xrS[tid][d], s);
        xnS[tid] = s;
    }
    __syncthreads();

    // ---- tail 2: posterior mean for this block's 16 test rows ----
    float acc[4][4];
    #pragma unroll
    for (int i = 0; i < 4; ++i)
        #pragma unroll
        for (int tt = 0; tt < 4; ++tt) acc[i][tt] = 0.f;
    for (int jb = 0; jb < NTR/64; ++jb) {
        int j = jb*64 + lane;
        const float4* aj4 = reinterpret_cast<const float4*>(ag + j*DIM);
        float4 A0=aj4[0], A1=aj4[1], A2=aj4[2], A3=aj4[3];
        float an = anormg[j];
        float4 Bj = qS[j];
        #pragma unroll
        for (int rr = 0; rr < 4; ++rr) {
            int row = 4*wv + rr;
            float dot;
            dot = xrS[row][0]*A0.x;             dot = fmaf(xrS[row][1], A0.y, dot);
            dot = fmaf(xrS[row][2], A0.z, dot);  dot = fmaf(xrS[row][3], A0.w, dot);
            dot = fmaf(xrS[row][4], A1.x, dot);  dot = fmaf(xrS[row][5], A1.y, dot);
            dot = fmaf(xrS[row][6], A1.z, dot);  dot = fmaf(xrS[row][7], A1.w, dot);
            dot = fmaf(xrS[row][8], A2.x, dot);  dot = fmaf(xrS[row][9], A2.y, dot);
            dot = fmaf(xrS[row][10],A2.z, dot);  dot = fmaf(xrS[row][11],A2.w, dot);
            dot = fmaf(xrS[row][12],A3.x, dot);  dot = fmaf(xrS[row][13],A3.y, dot);
            dot = fmaf(xrS[row][14],A3.z, dot);  dot = fmaf(xrS[row][15],A3.w, dot);
            float d2 = xnS[row] + an - 2.f*dot;
            float e = __expf(-0.5f * fmaxf(d2, 0.f));
            acc[rr][0] = fmaf(e, Bj.x, acc[rr][0]);
            acc[rr][1] = fmaf(e, Bj.y, acc[rr][1]);
            acc[rr][2] = fmaf(e, Bj.z, acc[rr][2]);
            acc[rr][3] = fmaf(e, Bj.w, acc[rr][3]);
        }
    }
    #pragma unroll
    for (int off = 32; off; off >>= 1)
        #pragma unroll
        for (int rr = 0; rr < 4; ++rr) {
            acc[rr][0] += __shfl_down(acc[rr][0], off);
            acc[rr][1] += __shfl_down(acc[rr][1], off);
            acc[rr][2] += __shfl_down(acc[rr][2], off);
            acc[rr][3] += __shfl_down(acc[rr][3], off);
        }
    if (lane == 0) {
        float m0 = mc[0], m1 = mc[1], m2 = mc[2], m3 = mc[3];
        #pragma unroll
        for (int rr = 0; rr < 4; ++rr) {
            float4 o;
            o.x = m0 + acc[rr][0]; o.y = m1 + acc[rr][1];
            o.z = m2 + acc[rr][2]; o.w = m3 + acc[rr][3];
            reinterpret_cast<float4*>(out)[b*16 + 4*wv + rr] = o;
        }
    }
}

extern "C" void kernel_launch(void* const* d_in, const int* in_sizes, int n_in,
                              void* d_out, int out_size, void* d_ws, size_t ws_size,
                              hipStream_t stream) {
    const float* x  = (const float*)d_in[0];
    const float* tx = (const float*)d_in[1];
    const float* ty = (const float*)d_in[2];
    const float* ls = (const float*)d_in[3];
    const float* mc = (const float*)d_in[4];
    const float* tf = (const float*)d_in[5];
    const float* tv = (const float*)d_in[6];
    const float* tn = (const float*)d_in[7];
    const float* nz = (const float*)d_in[8];

    float* ws    = (float*)d_ws;
    float* a     = ws + OFF_A;
    float* anorm = ws + OFF_ANORM;
    float* r     = ws + OFF_R;
    u64*   mt    = (u64*)(ws + OFF_MT);
    u64*   gt    = (u64*)(ws + OFF_GT);
    u64*   dt    = (u64*)(ws + OFF_DT);
    u64*   bt    = (u64*)(ws + OFF_BT);
    float* outp  = (float*)d_out;

    k_prep<<<NTR/256, 256, 0, stream>>>(tx, ty, ls, mc, a, anorm, r, mt);

    void* args[] = { (void*)&x, (void*)&ls, (void*)&mc,
                     (void*)&tf, (void*)&tv, (void*)&tn, (void*)&nz,
                     (void*)&a, (void*)&anorm, (void*)&r,
                     (void*)&mt, (void*)&gt, (void*)&dt, (void*)&bt,
                     (void*)&outp };
    hipLaunchCooperativeKernel((void*)k_pcg, dim3(NBLK), dim3(256), args, 0, stream);
}

// Round 7
// 99.663 us; speedup vs baseline: 1.0934x; 1.0934x over previous
//
#include <hip/hip_runtime.h>
#include <math.h>

#define NTR 2048
#define MTE 4096
#define DIM 16
#define TT 4
#define NT 8192          // NTR * TT
#define KIT 26           // max preconditioned PIPECG iterations
#define NBLK 256         // persistent blocks (1 per CU)
#define ROWS 8           // train rows per block
#define TOL2 1e-8f       // exit: gamma <= TOL2 * gamma0

typedef unsigned long long u64;

// workspace layout (float offsets; u64 regions 8B-aligned)
#define OFF_A     0                       // scaled train coords  NTR x DIM
#define OFF_ANORM (OFF_A + NTR*DIM)       // row norms            NTR
#define OFF_M     (OFF_ANORM + NTR)       // m vector, 2 slots    2*NT floats
#define OFF_X     (OFF_M + 2*NT)          // x vector (1 slot)    NT floats
#define OFF_GT    (OFF_X + NT)            // gamma sentinels      u64[2*NBLK]
#define OFF_DT    (OFF_GT + 4*NBLK)       // delta sentinels      u64[2*NBLK]

__device__ __forceinline__ u64 tagw(unsigned g, float v) {
    return ((u64)g << 32) | (u64)__float_as_uint(v);
}
__device__ __forceinline__ float payf(u64 w) { return __uint_as_float((unsigned)w); }
__device__ __forceinline__ unsigned tago(u64 w) { return (unsigned)(w >> 32); }

// prep: scaled coords + norms; zero sentinel words (replay-safe).
__global__ void k_prep(const float* __restrict__ tx, const float* __restrict__ ls,
                       float* __restrict__ a, float* __restrict__ anorm,
                       u64* __restrict__ tags) {
    int n = blockIdx.x * 256 + threadIdx.x;   // 8 blocks x 256 = 2048
    if (n < 1024) tags[n] = 0ULL;             // gt+dt contiguous: 1024 u64
    float an = 0.f;
    #pragma unroll
    for (int d = 0; d < DIM; ++d) {
        float v = tx[n*DIM + d] / ls[d];
        a[n*DIM + d] = v;
        an = fmaf(v, v, an);
    }
    anorm[n] = an;
}

// Persistent pipelined PCG (Ghysels-Vanroose), block-Jacobi M^-1 = I (x) C,
// C = (Kt+D)^-1 by Sherman-Morrison. One payload-sentinel exchange per
// iteration; m and x are plain floats whose visibility is guaranteed by the
// sentinel poll (+acquire). First matvec input u0 = C(y-mc) is computed
// redundantly from ty (no exchange). x rides along with every m publish so
// the tail needs no exchange either.
__global__ __launch_bounds__(256, 1) void k_pcg(
    const float* __restrict__ xte, const float* __restrict__ ty,
    const float* __restrict__ ls,  const float* __restrict__ mc,
    const float* __restrict__ tf,  const float* __restrict__ tv,
    const float* __restrict__ tn,  const float* __restrict__ nz,
    const float* __restrict__ ag,  const float* __restrict__ anormg,
    float* __restrict__ mbuf, float* __restrict__ xg,
    u64* __restrict__ gt, u64* __restrict__ dt,
    float* __restrict__ out)
{
    __shared__ float KxxS[ROWS][NTR];      // 64 KB
    __shared__ float arowS[ROWS][DIM];
    __shared__ float anormS[ROWS];
    __shared__ float uSm[32];
    __shared__ float xSl[32], rSl[32], uSl[32], wSl[32];
    __shared__ float pSl[32], sSl[32], zSl[32], qSl[32], mSl[32];
    __shared__ float scal[2];
    __shared__ float xrS[16][DIM];
    __shared__ float xnS[16];

    const int tid = threadIdx.x;
    const int b = blockIdx.x;
    const int wv = tid >> 6, lane = tid & 63;
    const int i0 = b * ROWS;
    const int sl = lane & 31;
    const int pbase = lane & ~3;

    const float f0=tf[0], f1=tf[1], f2=tf[2], f3=tf[3];
    const float K00=fmaf(f0,f0,tv[0]), K01=f0*f1, K02=f0*f2, K03=f0*f3;
    const float K11=fmaf(f1,f1,tv[1]), K12=f1*f2, K13=f1*f3;
    const float K22=fmaf(f2,f2,tv[2]), K23=f2*f3;
    const float K33=fmaf(f3,f3,tv[3]);
    const float dz = nz[0];
    const int   t  = lane & 3;
    const float dn_t = tn[t] + dz;
    const float mc0 = mc[0], mc1 = mc[1], mc2 = mc[2], mc3 = mc[3];
    // C = (Kt + D)^-1 via Sherman-Morrison: full matrix + per-lane row t
    const float g0v=tv[0]+tn[0]+dz, g1v=tv[1]+tn[1]+dz, g2v=tv[2]+tn[2]+dz, g3v=tv[3]+tn[3]+dz;
    const float c0=1.f/g0v, c1=1.f/g1v, c2=1.f/g2v, c3=1.f/g3v;
    const float up0=c0*f0, up1=c1*f1, up2=c2*f2, up3=c3*f3;
    const float rden = 1.f/(1.f + f0*up0 + f1*up1 + f2*up2 + f3*up3);
    const float C00=c0-up0*up0*rden, C01=-up0*up1*rden, C02=-up0*up2*rden, C03=-up0*up3*rden;
    const float C11=c1-up1*up1*rden, C12=-up1*up2*rden, C13=-up1*up3*rden;
    const float C22=c2-up2*up2*rden, C23=-up2*up3*rden;
    const float C33=c3-up3*up3*rden;
    const float upt = (t==0)?up0:(t==1)?up1:(t==2)?up2:up3;
    const float Ct0 = ((t==0)?c0:0.f) - upt*up0*rden;
    const float Ct1 = ((t==1)?c1:0.f) - upt*up1*rden;
    const float Ct2 = ((t==2)?c2:0.f) - upt*up2*rden;
    const float Ct3 = ((t==3)?c3:0.f) - upt*up3*rden;

    if (tid < ROWS*DIM) arowS[tid >> 4][tid & 15] = ag[i0*DIM + tid];
    if (tid < ROWS) anormS[tid] = anormg[i0 + tid];
    __syncthreads();

    // ---- phase A (local, no exchange): own slices r0, u0 = C r0; gamma0 part
    float gpart = 0.f;
    if (wv == 0) {
        float rv = (lane < 32) ? (ty[i0*TT + lane] - ((t==0)?mc0:(t==1)?mc1:(t==2)?mc2:mc3)) : 0.f;
        float r0s = __shfl(rv, pbase+0), r1s = __shfl(rv, pbase+1);
        float r2s = __shfl(rv, pbase+2), r3s = __shfl(rv, pbase+3);
        float uv = Ct0*r0s + Ct1*r1s + Ct2*r2s + Ct3*r3s;
        if (lane < 32) {
            rSl[lane]=rv; uSl[lane]=uv;
            xSl[lane]=0.f; pSl[lane]=0.f; sSl[lane]=0.f; zSl[lane]=0.f; qSl[lane]=0.f;
        }
        float g = (lane < 32) ? rv*uv : 0.f;
        #pragma unroll
        for (int off = 32; off; off >>= 1) g += __shfl_down(g, off);
        gpart = g;                         // valid in lane 0
    }

    // ---- build own Kxx rows in LDS ----
    for (int j = tid; j < NTR; j += 256) {
        const float4* aj4 = reinterpret_cast<const float4*>(ag + j*DIM);
        float4 A0=aj4[0], A1=aj4[1], A2=aj4[2], A3=aj4[3];
        float an = anormg[j];
        #pragma unroll
        for (int rr = 0; rr < ROWS; ++rr) {
            float dot;
            dot = arowS[rr][0]*A0.x;            dot = fmaf(arowS[rr][1], A0.y, dot);
            dot = fmaf(arowS[rr][2], A0.z, dot); dot = fmaf(arowS[rr][3], A0.w, dot);
            dot = fmaf(arowS[rr][4], A1.x, dot); dot = fmaf(arowS[rr][5], A1.y, dot);
            dot = fmaf(arowS[rr][6], A1.z, dot); dot = fmaf(arowS[rr][7], A1.w, dot);
            dot = fmaf(arowS[rr][8], A2.x, dot); dot = fmaf(arowS[rr][9], A2.y, dot);
            dot = fmaf(arowS[rr][10],A2.z, dot); dot = fmaf(arowS[rr][11],A2.w, dot);
            dot = fmaf(arowS[rr][12],A3.x, dot); dot = fmaf(arowS[rr][13],A3.y, dot);
            dot = fmaf(arowS[rr][14],A3.z, dot); dot = fmaf(arowS[rr][15],A3.w, dot);
            float d2 = anormS[rr] + an - 2.f*dot;
            KxxS[rr][j] = __expf(-0.5f * fmaxf(d2, 0.f));
        }
    }
    __syncthreads();

    const int r0_ = 2*wv, r1_ = r0_ + 1;

    // butterfly + uSm write helper
    auto finrows = [&](float a00,float a01,float a02,float a03,
                       float a10,float a11,float a12,float a13) {
        #pragma unroll
        for (int off = 32; off; off >>= 1) {
            a00 += __shfl_down(a00,off); a01 += __shfl_down(a01,off);
            a02 += __shfl_down(a02,off); a03 += __shfl_down(a03,off);
            a10 += __shfl_down(a10,off); a11 += __shfl_down(a11,off);
            a12 += __shfl_down(a12,off); a13 += __shfl_down(a13,off);
        }
        if (lane == 0) {
            uSm[r0_*4+0]=a00; uSm[r0_*4+1]=a01; uSm[r0_*4+2]=a02; uSm[r0_*4+3]=a03;
            uSm[r1_*4+0]=a10; uSm[r1_*4+1]=a11; uSm[r1_*4+2]=a12; uSm[r1_*4+3]=a13;
        }
        __syncthreads();
    };

    // ---- init matvec: u0 generated on the fly from ty (all blocks, local) ----
    {
        float a00=0,a01=0,a02=0,a03=0,a10=0,a11=0,a12=0,a13=0;
        const float4* ty4 = reinterpret_cast<const float4*>(ty);
        for (int jb = 0; jb < NTR/64; ++jb) {
            int j = jb*64 + lane;
            float4 yv = ty4[j];
            float rx = yv.x - mc0, ry = yv.y - mc1, rz = yv.z - mc2, rw = yv.w - mc3;
            float ux = C00*rx + C01*ry + C02*rz + C03*rw;
            float uy = C01*rx + C11*ry + C12*rz + C13*rw;
            float uz = C02*rx + C12*ry + C22*rz + C23*rw;
            float uw = C03*rx + C13*ry + C23*rz + C33*rw;
            float qx = K00*ux + K01*uy + K02*uz + K03*uw;
            float qy = K01*ux + K11*uy + K12*uz + K13*uw;
            float qz = K02*ux + K12*uy + K22*uz + K23*uw;
            float qw = K03*ux + K13*uy + K23*uz + K33*uw;
            float k0 = KxxS[r0_][j], k1 = KxxS[r1_][j];
            a00 = fmaf(k0,qx,a00); a01 = fmaf(k0,qy,a01);
            a02 = fmaf(k0,qz,a02); a03 = fmaf(k0,qw,a03);
            a10 = fmaf(k1,qx,a10); a11 = fmaf(k1,qy,a11);
            a12 = fmaf(k1,qz,a12); a13 = fmaf(k1,qw,a13);
        }
        finrows(a00,a01,a02,a03,a10,a11,a12,a13);
    }

    // wave0-only: poll all sentinels of `tag`, fixed-order sum, acquire.
    auto scalred = [&](unsigned tag) {
        u64* gs = gt + (tag & 1u)*NBLK;
        u64* ds = dt + (tag & 1u)*NBLK;
        u64 ga[4], da[4];
        for (;;) {
            bool ok = true;
            #pragma unroll
            for (int k2 = 0; k2 < 4; ++k2) {
                ga[k2] = __hip_atomic_load(&gs[lane + 64*k2], __ATOMIC_RELAXED, __HIP_MEMORY_SCOPE_AGENT);
                da[k2] = __hip_atomic_load(&ds[lane + 64*k2], __ATOMIC_RELAXED, __HIP_MEMORY_SCOPE_AGENT);
                ok = ok && (tago(ga[k2]) >= tag) && (tago(da[k2]) >= tag);
            }
            if (__all(ok)) break;
            __builtin_amdgcn_s_sleep(1);
        }
        float g  = payf(ga[0]) + payf(ga[1]) + payf(ga[2]) + payf(ga[3]);
        float dl = payf(da[0]) + payf(da[1]) + payf(da[2]) + payf(da[3]);
        #pragma unroll
        for (int off = 32; off; off >>= 1) { g += __shfl_down(g,off); dl += __shfl_down(dl,off); }
        if (lane == 0) { scal[0] = g; scal[1] = dl; }
        (void)__hip_atomic_load(&gs[b], __ATOMIC_ACQUIRE, __HIP_MEMORY_SCOPE_AGENT);
    };

    // ---- event 1: w0 = A u0; m0 = C w0 -> slot 1; x(=0); {gamma0, delta0} ----
    if (wv == 0) {
        float uv = uSl[sl];
        float wn = uSm[sl] + dn_t * uv;
        float w0s = __shfl(wn, pbase+0), w1s = __shfl(wn, pbase+1);
        float w2s = __shfl(wn, pbase+2), w3s = __shfl(wn, pbase+3);
        float mn = Ct0*w0s + Ct1*w1s + Ct2*w2s + Ct3*w3s;
        if (lane < 32) {
            wSl[lane]=wn; mSl[lane]=mn;
            __hip_atomic_store(&mbuf[1*NT + i0*TT + lane], mn,
                               __ATOMIC_RELAXED, __HIP_MEMORY_SCOPE_AGENT);
            __hip_atomic_store(&xg[i0*TT + lane], 0.f,
                               __ATOMIC_RELAXED, __HIP_MEMORY_SCOPE_AGENT);
        }
        float dl = (lane < 32) ? wn*uv : 0.f;
        #pragma unroll
        for (int off = 32; off; off >>= 1) dl += __shfl_down(dl, off);
        asm volatile("s_waitcnt vmcnt(0)" ::: "memory");
        if (lane == 0) {
            __hip_atomic_store(&dt[1*NBLK + b], tagw(1u, dl), __ATOMIC_RELAXED, __HIP_MEMORY_SCOPE_AGENT);
            __hip_atomic_store(&gt[1*NBLK + b], tagw(1u, gpart), __ATOMIC_RELAXED, __HIP_MEMORY_SCOPE_AGENT);
        }
        scalred(1u);
    }
    __syncthreads();

    // ---- main loop: iteration it consumes event it+1 (scal + m slot (it+1)&1),
    //      publishes event it+2 (m slot (it+2)&1, x, sentinels) ----
    float gamma_prev = 1.f, alpha_prev = 1.f, gamma0 = 0.f;
    float g1h = 1e30f, g2h = 1e30f;
    for (int it = 0; it < KIT; ++it) {
        float gam = scal[0], del = scal[1];
        if (it == 0) gamma0 = gam;
        if (!(gam > TOL2 * gamma0)) break;                 // converged / NaN
        if (it >= 6 && gam > 0.25f * g2h) break;           // fp32 stagnation
        float beta, alph;
        if (it == 0) { beta = 0.f; alph = gam / del; }
        else {
            beta = gam / gamma_prev;
            float den = del - beta * gam / alpha_prev;
            if (!(fabsf(den) > 1e-37f)) break;
            alph = gam / den;
        }

        // fused matvec: plain vectorized reads of m (visibility via sentinel)
        {
            const float4* m4 = reinterpret_cast<const float4*>(mbuf + ((it+1)&1)*NT);
            float a00=0,a01=0,a02=0,a03=0,a10=0,a11=0,a12=0,a13=0;
            for (int jb = 0; jb < NTR/64; ++jb) {
                int j = jb*64 + lane;
                float4 v = m4[j];
                float qx = K00*v.x + K01*v.y + K02*v.z + K03*v.w;
                float qy = K01*v.x + K11*v.y + K12*v.z + K13*v.w;
                float qz = K02*v.x + K12*v.y + K22*v.z + K23*v.w;
                float qw = K03*v.x + K13*v.y + K23*v.z + K33*v.w;
                float k0 = KxxS[r0_][j], k1 = KxxS[r1_][j];
                a00 = fmaf(k0,qx,a00); a01 = fmaf(k0,qy,a01);
                a02 = fmaf(k0,qz,a02); a03 = fmaf(k0,qw,a03);
                a10 = fmaf(k1,qx,a10); a11 = fmaf(k1,qy,a11);
                a12 = fmaf(k1,qz,a12); a13 = fmaf(k1,qw,a13);
            }
            finrows(a00,a01,a02,a03,a10,a11,a12,a13);
        }

        if (wv == 0) {
            const unsigned e2 = (unsigned)(it + 2);
            float mv = mSl[sl];
            float nv = uSm[sl] + dn_t * mv;            // full A m
            float zv = fmaf(beta, zSl[sl], nv);
            float qv = fmaf(beta, qSl[sl], mv);
            float sv = fmaf(beta, sSl[sl], wSl[sl]);
            float pv = fmaf(beta, pSl[sl], uSl[sl]);
            float xv = fmaf( alph, pv, xSl[sl]);
            float rv = fmaf(-alph, sv, rSl[sl]);
            float uv = fmaf(-alph, qv, uSl[sl]);
            float wn = fmaf(-alph, zv, wSl[sl]);
            float w0s = __shfl(wn, pbase+0), w1s = __shfl(wn, pbase+1);
            float w2s = __shfl(wn, pbase+2), w3s = __shfl(wn, pbase+3);
            float mn = Ct0*w0s + Ct1*w1s + Ct2*w2s + Ct3*w3s;
            if (lane < 32) {
                zSl[lane]=zv; qSl[lane]=qv; sSl[lane]=sv; pSl[lane]=pv;
                xSl[lane]=xv; rSl[lane]=rv; uSl[lane]=uv; wSl[lane]=wn; mSl[lane]=mn;
                __hip_atomic_store(&mbuf[(e2&1u)*NT + i0*TT + lane], mn,
                                   __ATOMIC_RELAXED, __HIP_MEMORY_SCOPE_AGENT);
                __hip_atomic_store(&xg[i0*TT + lane], xv,
                                   __ATOMIC_RELAXED, __HIP_MEMORY_SCOPE_AGENT);
            }
            float g  = (lane < 32) ? rv*uv : 0.f;
            float dl = (lane < 32) ? wn*uv : 0.f;
            #pragma unroll
            for (int off = 32; off; off >>= 1) { g += __shfl_down(g,off); dl += __shfl_down(dl,off); }
            asm volatile("s_waitcnt vmcnt(0)" ::: "memory");
            if (lane == 0) {
                __hip_atomic_store(&dt[(e2&1u)*NBLK + b], tagw(e2, dl), __ATOMIC_RELAXED, __HIP_MEMORY_SCOPE_AGENT);
                __hip_atomic_store(&gt[(e2&1u)*NBLK + b], tagw(e2, g),  __ATOMIC_RELAXED, __HIP_MEMORY_SCOPE_AGENT);
            }
            scalred(e2);
        }
        gamma_prev = gam; alpha_prev = alph;
        g2h = g1h; g1h = gam;
        __syncthreads();
    }

    // ---- tail: x already visible (published with the last consumed event).
    //      B_j = Kt * x_j computed on the fly; no exchange. ----
    {
        int row = tid >> 4, d = tid & 15;
        xrS[row][d] = xte[(b*16 + row)*DIM + d] / ls[d];
    }
    __syncthreads();
    if (tid < 16) {
        float s = 0.f;
        #pragma unroll
        for (int d = 0; d < DIM; ++d) s = fmaf(xrS[tid][d], xrS[tid][d], s);
        xnS[tid] = s;
    }
    __syncthreads();

    float acc[4][4];
    #pragma unroll
    for (int i = 0; i < 4; ++i)
        #pragma unroll
        for (int tt = 0; tt < 4; ++tt) acc[i][tt] = 0.f;
    const float4* xg4 = reinterpret_cast<const float4*>(xg);
    for (int jb = 0; jb < NTR/64; ++jb) {
        int j = jb*64 + lane;
        const float4* aj4 = reinterpret_cast<const float4*>(ag + j*DIM);
        float4 A0=aj4[0], A1=aj4[1], A2=aj4[2], A3=aj4[3];
        float an = anormg[j];
        float4 xj = xg4[j];
        float Bx = K00*xj.x + K01*xj.y + K02*xj.z + K03*xj.w;
        float By = K01*xj.x + K11*xj.y + K12*xj.z + K13*xj.w;
        float Bz = K02*xj.x + K12*xj.y + K22*xj.z + K23*xj.w;
        float Bw = K03*xj.x + K13*xj.y + K23*xj.z + K33*xj.w;
        #pragma unroll
        for (int rr = 0; rr < 4; ++rr) {
            int row = 4*wv + rr;
            float dot;
            dot = xrS[row][0]*A0.x;             dot = fmaf(xrS[row][1], A0.y, dot);
            dot = fmaf(xrS[row][2], A0.z, dot);  dot = fmaf(xrS[row][3], A0.w, dot);
            dot = fmaf(xrS[row][4], A1.x, dot);  dot = fmaf(xrS[row][5], A1.y, dot);
            dot = fmaf(xrS[row][6], A1.z, dot);  dot = fmaf(xrS[row][7], A1.w, dot);
            dot = fmaf(xrS[row][8], A2.x, dot);  dot = fmaf(xrS[row][9], A2.y, dot);
            dot = fmaf(xrS[row][10],A2.z, dot);  dot = fmaf(xrS[row][11],A2.w, dot);
            dot = fmaf(xrS[row][12],A3.x, dot);  dot = fmaf(xrS[row][13],A3.y, dot);
            dot = fmaf(xrS[row][14],A3.z, dot);  dot = fmaf(xrS[row][15],A3.w, dot);
            float d2 = xnS[row] + an - 2.f*dot;
            float e = __expf(-0.5f * fmaxf(d2, 0.f));
            acc[rr][0] = fmaf(e, Bx, acc[rr][0]);
            acc[rr][1] = fmaf(e, By, acc[rr][1]);
            acc[rr][2] = fmaf(e, Bz, acc[rr][2]);
            acc[rr][3] = fmaf(e, Bw, acc[rr][3]);
        }
    }
    #pragma unroll
    for (int off = 32; off; off >>= 1)
        #pragma unroll
        for (int rr = 0; rr < 4; ++rr) {
            acc[rr][0] += __shfl_down(acc[rr][0], off);
            acc[rr][1] += __shfl_down(acc[rr][1], off);
            acc[rr][2] += __shfl_down(acc[rr][2], off);
            acc[rr][3] += __shfl_down(acc[rr][3], off);
        }
    if (lane == 0) {
        #pragma unroll
        for (int rr = 0; rr < 4; ++rr) {
            float4 o;
            o.x = mc0 + acc[rr][0]; o.y = mc1 + acc[rr][1];
            o.z = mc2 + acc[rr][2]; o.w = mc3 + acc[rr][3];
            reinterpret_cast<float4*>(out)[b*16 + 4*wv + rr] = o;
        }
    }
}

extern "C" void kernel_launch(void* const* d_in, const int* in_sizes, int n_in,
                              void* d_out, int out_size, void* d_ws, size_t ws_size,
                              hipStream_t stream) {
    const float* x  = (const float*)d_in[0];
    const float* tx = (const float*)d_in[1];
    const float* ty = (const float*)d_in[2];
    const float* ls = (const float*)d_in[3];
    const float* mc = (const float*)d_in[4];
    const float* tf = (const float*)d_in[5];
    const float* tv = (const float*)d_in[6];
    const float* tn = (const float*)d_in[7];
    const float* nz = (const float*)d_in[8];

    float* ws    = (float*)d_ws;
    float* a     = ws + OFF_A;
    float* anorm = ws + OFF_ANORM;
    float* m     = ws + OFF_M;
    float* xv    = ws + OFF_X;
    u64*   gtp   = (u64*)(ws + OFF_GT);
    u64*   dtp   = (u64*)(ws + OFF_DT);
    float* outp  = (float*)d_out;

    k_prep<<<NTR/256, 256, 0, stream>>>(tx, ls, a, anorm, gtp);

    void* args[] = { (void*)&x, (void*)&ty, (void*)&ls, (void*)&mc,
                     (void*)&tf, (void*)&tv, (void*)&tn, (void*)&nz,
                     (void*)&a, (void*)&anorm,
                     (void*)&m, (void*)&xv, (void*)&gtp, (void*)&dtp,
                     (void*)&outp };
    hipLaunchCooperativeKernel((void*)k_pcg, dim3(NBLK), dim3(256), args, 0, stream);
}